// Round 2
// baseline (124.988 us; speedup 1.0000x reference)
//
#include <hip/hip_runtime.h>
#include <math.h>

#define D_MODEL 1024
#define N_STATE 64
#define L_LEN   2048

// One block per d-channel. Threads 0..63 precompute per-n parameters in
// double precision (once per block, negligible cost), then all 256 threads
// evaluate K[d,l] in closed form:
//   K[d,l] = sum_n |w_n| * |Abar_n|^l * cos(2*pi*(l*theta_rev_n + phi_rev_n))
// theta_rev and log2|Abar| are split hi(12-bit)/lo so l*hi is EXACT in fp32
// (l <= 2047 < 2^11, hi has 12 mantissa bits -> 23-bit product).
__global__ __launch_bounds__(256) void s4d_kernel(
    const float* __restrict__ A_real, const float* __restrict__ A_imag,
    const float* __restrict__ B, const float* __restrict__ C,
    const float* __restrict__ Dv, const float* __restrict__ log_dt,
    float* __restrict__ out)
{
    __shared__ float s_th_hi[N_STATE], s_th_lo[N_STATE], s_ph[N_STATE];
    __shared__ float s_la_hi[N_STATE], s_la_lo[N_STATE], s_lw[N_STATE];

    const int d = blockIdx.x;
    const int t = threadIdx.x;

    if (t < N_STATE) {
        const int n = t;
        const double dt = exp((double)log_dt[d]);
        // z = dt*A/2
        const double zr = 0.5 * dt * (double)A_real[n];
        const double zi = 0.5 * dt * (double)A_imag[n];
        // Abar = (1+z)/(1-z);  (1-z) = dr + i*di with dr=1-zr, di=-zi
        const double dr = 1.0 - zr, di = -zi;
        const double inv = 1.0 / (dr*dr + di*di);
        const double nr = 1.0 + zr, ni = zi;
        const double sr = (nr*dr + ni*di) * inv;
        const double si = (ni*dr - nr*di) * inv;
        // Bbar = dt*B[n][d]/(1-z) = dt*B * (dr - i*di) * inv ; -di = zi
        const double dtB = dt * (double)B[n*D_MODEL + d];
        const double br = dtB * dr * inv;
        const double bi = dtB * zi * inv;
        // w = Cc * Bbar
        const double cr = (double)C[(d*N_STATE + n)*2 + 0];
        const double ci = (double)C[(d*N_STATE + n)*2 + 1];
        const double wr = cr*br - ci*bi;
        const double wi = cr*bi + ci*br;

        const double INV2PI = 0.15915494309189535;
        const double threv = atan2(si, sr) * INV2PI;       // (-0.5, 0.5]
        const double la    = 0.5 * log2(sr*sr + si*si);     // log2 |Abar| (<0)
        const double w2    = wr*wr + wi*wi;
        const double lw    = 0.5 * log2(fmax(w2, 1e-60));   // log2 |w|
        const double phrev = atan2(wi, wr) * INV2PI;

        // hi = nearest multiple of 2^-12 -> exact fp32, l*hi exact fp32
        const double th_hi = nearbyint(threv * 4096.0) * (1.0 / 4096.0);
        const double la_hi = nearbyint(la    * 4096.0) * (1.0 / 4096.0);
        s_th_hi[n] = (float)th_hi;
        s_th_lo[n] = (float)(threv - th_hi);
        s_la_hi[n] = (float)la_hi;
        s_la_lo[n] = (float)(la - la_hi);
        s_lw[n]    = (float)lw;
        s_ph[n]    = (float)phrev;
    }
    __syncthreads();

    #pragma unroll
    for (int j = 0; j < L_LEN / 256; ++j) {
        const int l = j * 256 + t;
        const float lf = (float)l;
        float acc = 0.0f;
        #pragma unroll 4
        for (int n = 0; n < N_STATE; ++n) {
            // amplitude = exp2(l*la + lw), la split hi/lo
            float e1  = fmaf(lf, s_la_lo[n], s_lw[n]);
            float e2  = fmaf(lf, s_la_hi[n], e1);
            float amp = exp2f(e2);
            // phase in revolutions: fract(l*th_hi) exact, then lo correction
            float p1 = lf * s_th_hi[n];                  // exact product
            float f1 = __builtin_amdgcn_fractf(p1);
            float p2 = fmaf(lf, s_th_lo[n], s_ph[n]);
            float ph = __builtin_amdgcn_fractf(f1 + p2);
            float c  = __builtin_amdgcn_cosf(ph);        // v_cos_f32: cos(2*pi*x)
            acc = fmaf(amp, c, acc);
        }
        if (l == 0) acc += Dv[d];
        out[d * L_LEN + l] = acc;
    }
}

extern "C" void kernel_launch(void* const* d_in, const int* in_sizes, int n_in,
                              void* d_out, int out_size, void* d_ws, size_t ws_size,
                              hipStream_t stream) {
    const float* A_real = (const float*)d_in[0];
    const float* A_imag = (const float*)d_in[1];
    const float* B      = (const float*)d_in[2];
    const float* C      = (const float*)d_in[3];
    const float* Dv     = (const float*)d_in[4];
    const float* log_dt = (const float*)d_in[5];
    float* out = (float*)d_out;
    (void)in_sizes; (void)n_in; (void)d_ws; (void)ws_size; (void)out_size;

    s4d_kernel<<<dim3(D_MODEL), dim3(256), 0, stream>>>(
        A_real, A_imag, B, C, Dv, log_dt, out);
}

// Round 3
// 84.557 us; speedup vs baseline: 1.4782x; 1.4782x over previous
//
#include <hip/hip_runtime.h>
#include <math.h>

#define D_MODEL 1024
#define N_STATE 64
#define L_LEN   2048

// Closed-form single-term eval (validated in round 0, absmax 0.0039):
// |w| * |Abar|^l * cos(2*pi*(l*theta + phi)), with theta/log2|Abar| split
// hi(multiple of 2^-12)/lo so l*hi is exact in fp32 for l < 2^11.
__device__ __forceinline__ float eval_term(float lf,
                                           float th_hi, float th_lo, float ph0,
                                           float la_hi, float la_lo, float lw) {
    float amp = exp2f(fmaf(lf, la_hi, fmaf(lf, la_lo, lw)));
    float f1  = __builtin_amdgcn_fractf(lf * th_hi);           // exact product
    float ph  = __builtin_amdgcn_fractf(f1 + fmaf(lf, th_lo, ph0));
    return amp * __builtin_amdgcn_cosf(ph);                    // cos(2*pi*x)
}

// One block per d (256 thr = 4 waves; wave w owns l in [512w, 512w+512)).
// Lane split: q = lane>>4 (state quartet), g = lane&15 (l offset).
// Each lane runs 16 recurrence chains (states n = 4c+q) along l = lbase+g
// with stride 16:  y_{i+1} = 2Re(Abar^16) y_i - |Abar^16|^2 y_{i-1}.
// Per step: tree-sum 16 chains + 2-stage shfl_xor butterfly over q -> full
// 64-state sum; the q==(i&3) quartet stores 16 consecutive floats (64B).
__global__ __launch_bounds__(256) void s4d_kernel(
    const float* __restrict__ A_real, const float* __restrict__ A_imag,
    const float* __restrict__ B, const float* __restrict__ C,
    const float* __restrict__ Dv, const float* __restrict__ log_dt,
    float* __restrict__ out)
{
    __shared__ float s_th_hi[N_STATE], s_th_lo[N_STATE], s_ph[N_STATE];
    __shared__ float s_la_hi[N_STATE], s_la_lo[N_STATE], s_lw[N_STATE];
    __shared__ float s_ar[N_STATE], s_am[N_STATE];

    const int d = blockIdx.x;
    const int t = threadIdx.x;

    if (t < N_STATE) {
        const int n = t;
        const double dt = exp((double)log_dt[d]);
        const double zr = 0.5 * dt * (double)A_real[n];
        const double zi = 0.5 * dt * (double)A_imag[n];
        const double dr = 1.0 - zr, di = -zi;
        const double inv = 1.0 / (dr*dr + di*di);
        const double nr = 1.0 + zr, ni = zi;
        const double sr = (nr*dr + ni*di) * inv;      // Abar
        const double si = (ni*dr - nr*di) * inv;
        const double dtB = dt * (double)B[n*D_MODEL + d];
        const double br = dtB * dr * inv;
        const double bi = dtB * zi * inv;
        const double cr = (double)C[(d*N_STATE + n)*2 + 0];
        const double ci = (double)C[(d*N_STATE + n)*2 + 1];
        const double wr = cr*br - ci*bi;              // w = Cc * Bbar
        const double wi = cr*bi + ci*br;

        const double INV2PI = 0.15915494309189535;
        const double threv = atan2(si, sr) * INV2PI;
        const double la    = 0.5 * log2(sr*sr + si*si);
        const double w2    = wr*wr + wi*wi;
        const double lw    = 0.5 * log2(fmax(w2, 1e-60));
        const double phrev = atan2(wi, wr) * INV2PI;

        const double th_hi = nearbyint(threv * 4096.0) * (1.0 / 4096.0);
        const double la_hi = nearbyint(la    * 4096.0) * (1.0 / 4096.0);
        s_th_hi[n] = (float)th_hi;
        s_th_lo[n] = (float)(threv - th_hi);
        s_la_hi[n] = (float)la_hi;
        s_la_lo[n] = (float)(la - la_hi);
        s_lw[n]    = (float)lw;
        s_ph[n]    = (float)phrev;

        // Abar^16 by 4 complex squarings in double (exact enough):
        double pr = sr, pq = si;
        #pragma unroll
        for (int k = 0; k < 4; ++k) {
            double a2 = pr*pr - pq*pq;
            double b2 = 2.0*pr*pq;
            pr = a2; pq = b2;
        }
        s_ar[n] = (float)(2.0 * pr);          // 2*Re(Abar^16)
        s_am[n] = (float)(pr*pr + pq*pq);     // |Abar^16|^2
    }
    __syncthreads();

    const int wv   = t >> 6;
    const int lane = t & 63;
    const int q    = lane >> 4;
    const int g    = lane & 15;
    const int lbase = wv * 512 + g;
    const float dval = Dv[d];

    float y0[16], y1[16], ar[16], am[16];
    #pragma unroll
    for (int c = 0; c < 16; ++c) {
        const int n = (c << 2) | q;
        const float th_hi = s_th_hi[n], th_lo = s_th_lo[n], ph0 = s_ph[n];
        const float la_hi = s_la_hi[n], la_lo = s_la_lo[n], lw = s_lw[n];
        ar[c] = s_ar[n];
        am[c] = s_am[n];
        y0[c] = eval_term((float)lbase,        th_hi, th_lo, ph0, la_hi, la_lo, lw);
        y1[c] = eval_term((float)(lbase + 16), th_hi, th_lo, ph0, la_hi, la_lo, lw);
    }

    float* __restrict__ op = out + (size_t)d * L_LEN;

    #pragma unroll
    for (int i = 0; i < 32; ++i) {
        // tree-sum this lane's 16 chains (value at l = lbase + 16*i)
        float r8[8];
        #pragma unroll
        for (int k = 0; k < 8; ++k) r8[k] = y0[2*k] + y0[2*k+1];
        float r4a = r8[0] + r8[1], r4b = r8[2] + r8[3];
        float r4c = r8[4] + r8[5], r4d = r8[6] + r8[7];
        float sum = (r4a + r4b) + (r4c + r4d);
        // butterfly over the 4 state-quartets (lane bits 4,5)
        sum += __shfl_xor(sum, 16);
        sum += __shfl_xor(sum, 32);
        if (q == (i & 3)) {
            const int l = lbase + 16 * i;
            float v = sum;
            if (l == 0) v += dval;            // D * delta[0]
            op[l] = v;                        // 16 consecutive floats: 64B store
        }
        // advance all chains: y_{i+2} = ar*y_{i+1} - am*y_i
        #pragma unroll
        for (int c = 0; c < 16; ++c) {
            float yn = fmaf(ar[c], y1[c], -(am[c] * y0[c]));
            y0[c] = y1[c];
            y1[c] = yn;
        }
    }
}

extern "C" void kernel_launch(void* const* d_in, const int* in_sizes, int n_in,
                              void* d_out, int out_size, void* d_ws, size_t ws_size,
                              hipStream_t stream) {
    const float* A_real = (const float*)d_in[0];
    const float* A_imag = (const float*)d_in[1];
    const float* B      = (const float*)d_in[2];
    const float* C      = (const float*)d_in[3];
    const float* Dv     = (const float*)d_in[4];
    const float* log_dt = (const float*)d_in[5];
    float* out = (float*)d_out;
    (void)in_sizes; (void)n_in; (void)d_ws; (void)ws_size; (void)out_size;

    s4d_kernel<<<dim3(D_MODEL), dim3(256), 0, stream>>>(
        A_real, A_imag, B, C, Dv, log_dt, out);
}